// Round 8
// baseline (290.570 us; speedup 1.0000x reference)
//
#include <hip/hip_runtime.h>

typedef __attribute__((ext_vector_type(8))) short short8;
typedef __attribute__((ext_vector_type(4))) float floatx4;

#define MFMA16(a, b, c) __builtin_amdgcn_mfma_f32_16x16x32_bf16(a, b, c, 0, 0, 0)

__device__ __forceinline__ short f2bf(float f) {
    unsigned int u = __float_as_uint(f);
    u = u + 0x7fffu + ((u >> 16) & 1u);
    return (short)(u >> 16);
}

// ---------------------------------------------------------------------------
// Kernel 0: convert Wq/Wk/Wv fp32 [1024][128] -> bf16 in MFMA FRAGMENT ORDER:
// wtf[which][ks(32)][nt(8)][lane(64)][e(8)], value = W[k][n] with
// n = 16*nt + (lane&15), k = 32*ks + 8*(lane>>4) + e.  A wave's B-fragment
// load is then ONE coalesced 1KB block (base + lane*16B): no gather, no LDS.
// ---------------------------------------------------------------------------
__global__ __launch_bounds__(256) void wconv_kernel(const float* __restrict__ Wq,
                                                    const float* __restrict__ Wk,
                                                    const float* __restrict__ Wv,
                                                    short* __restrict__ wtf) {
    int idx = blockIdx.x * 256 + threadIdx.x;   // < 3*131072
    int w = idx >> 17;
    int rem = idx & 131071;
    int ks = rem >> 12;
    int r2 = rem & 4095;
    int nt = r2 >> 9;
    int r3 = r2 & 511;
    int lane = r3 >> 3, e = r3 & 7;
    int q4 = lane >> 4, l16 = lane & 15;
    int n = 16 * nt + l16;
    int k = 32 * ks + 8 * q4 + e;
    const float* W = (w == 0) ? Wq : (w == 1) ? Wk : Wv;
    wtf[idx] = f2bf(W[k * 128 + n]);
}

// ---------------------------------------------------------------------------
// Kernel 1 (fused q/k/v): C = A[16384x1024](f32) * W (+bias) -> bf16.
// v8: REG-STAGED A (T14). Evidence r0-r7: HBM-sourced global_load_lds pins
// at ~2.1 TB/s in every structure; the register path measures 6.3 (m13).
// Per chunk (BK=128): A tile [32r][128k] = 16KB loaded as 4 float4/thread
// (512B contiguous per wave-instruction), ds_write_b128 with XOR swizzle
// at WRITE time, swizzled read (rule #21: both sides). 2-deep A reg banks
// (static names) -> the ds_write's dataflow vmcnt wait has ~1.5-interval
// lead >= HBM latency. B direct from fragment-packed wtf (L2), loaded at
// iter end so the in-order vmcnt chain never drags the A stream. ONE
// barrier/iter. 256 thr = 4 waves x (32r x 32c). Grid (512,3), 2 blocks/CU.
// ---------------------------------------------------------------------------
__global__ __launch_bounds__(256, 2) void proj_kernel(const float* __restrict__ Q,
                                                      const float* __restrict__ K,
                                                      const float* __restrict__ V,
                                                      const short* __restrict__ wtf,
                                                      const float* __restrict__ bq,
                                                      const float* __restrict__ bk,
                                                      const float* __restrict__ bv,
                                                      short* __restrict__ qo,
                                                      short* __restrict__ ko,
                                                      short* __restrict__ vo) {
    alignas(16) __shared__ float Asl[2][32 * 128];  // 16KB/buf: [row][32 slots], slot=c^(r&15)
    const int t = threadIdx.x;                    // 0..255
    const int wv = t >> 6, L = t & 63;
    const int wn = wv;                            // wave's col group (32 cols)
    const int q4 = L >> 4, l16 = L & 15;
    const int which = blockIdx.y;
    const float* A = (which == 0) ? Q : (which == 1) ? K : V;
    const short* Wf = wtf + which * 131072;
    const float* bias = (which == 0) ? bq : (which == 1) ? bk : bv;
    const int m0 = blockIdx.x * 32;

    floatx4 acc[2][2];
#pragma unroll
    for (int rg = 0; rg < 2; rg++)
#pragma unroll
        for (int nt = 0; nt < 2; nt++) acc[rg][nt] = (floatx4)0.0f;

    float4 arA[4], arB[4];                        // 2-deep A staging banks
    short8 bfr[4][2];                             // B-frags for current chunk

    auto loadA = [&](int k0, float4 (&ar)[4]) {
#pragma unroll
        for (int j = 0; j < 4; j++) {
            int s = j * 256 + t, r = s >> 5, c = s & 31;   // [32r][32 slots]
            ar[j] = *(const float4*)(A + (size_t)(m0 + r) * 1024 + k0 + c * 4);
        }
    };
    auto writeA = [&](int buf, float4 (&ar)[4]) {
#pragma unroll
        for (int j = 0; j < 4; j++) {
            int s = j * 256 + t, r = s >> 5, c = s & 31;
            *(float4*)&Asl[buf][(r * 32 + (c ^ (r & 15))) * 4] = ar[j];
        }
    };
    auto loadB = [&](int kc) {
#pragma unroll
        for (int ks = 0; ks < 4; ks++)
#pragma unroll
            for (int nt = 0; nt < 2; nt++)
                bfr[ks][nt] = *(const short8*)(Wf +
                    (((size_t)(4 * kc + ks) * 8 + 2 * wn + nt) * 64 + L) * 8);
    };
    auto computeC = [&](int kc) {
#pragma unroll
        for (int ks = 0; ks < 4; ks++) {
            short8 af[2];
#pragma unroll
            for (int rg = 0; rg < 2; rg++) {
                int r = 16 * rg + l16;            // r&15 == l16
                int c0 = 8 * ks + 2 * q4;
                float4 f0 = *(float4*)&Asl[kc & 1][(r * 32 + (c0 ^ l16)) * 4];
                float4 f1 = *(float4*)&Asl[kc & 1][(r * 32 + ((c0 + 1) ^ l16)) * 4];
                short8 v;
                v[0] = f2bf(f0.x); v[1] = f2bf(f0.y); v[2] = f2bf(f0.z); v[3] = f2bf(f0.w);
                v[4] = f2bf(f1.x); v[5] = f2bf(f1.y); v[6] = f2bf(f1.z); v[7] = f2bf(f1.w);
                af[rg] = v;
            }
            __builtin_amdgcn_s_setprio(1);
#pragma unroll
            for (int nt = 0; nt < 2; nt++) {
                acc[0][nt] = MFMA16(af[0], bfr[ks][nt], acc[0][nt]);
                acc[1][nt] = MFMA16(af[1], bfr[ks][nt], acc[1][nt]);
            }
            __builtin_amdgcn_s_setprio(0);
        }
    };

#define PROJ_STEP(KC, LDBANK, WRBANK)                                       \
    {                                                                       \
        if ((KC) + 2 < 8) loadA(((KC) + 2) * 128, LDBANK);                  \
        __builtin_amdgcn_sched_barrier(0);                                  \
        computeC(KC);                                                       \
        if ((KC) + 1 < 8) {                                                 \
            loadB((KC) + 1);                                                \
            writeA(((KC) + 1) & 1, WRBANK);  /* dataflow vmcnt wait */      \
        }                                                                   \
        asm volatile("s_waitcnt lgkmcnt(0)" ::: "memory");                  \
        __builtin_amdgcn_sched_barrier(0);                                  \
        __builtin_amdgcn_s_barrier();                                       \
    }

    // prologue: LD(0)->A, LD(1)->B in flight; B(0); write buf0; barrier
    loadA(0, arA);
    loadA(128, arB);
    loadB(0);
    writeA(0, arA);                               // waits only arA (older than arB)
    asm volatile("s_waitcnt lgkmcnt(0)" ::: "memory");
    __builtin_amdgcn_sched_barrier(0);
    __builtin_amdgcn_s_barrier();

    for (int kc = 0; kc < 8; kc += 2) {
        PROJ_STEP(kc, arA, arB);                  // LD(kc+2)->A, write(kc+1)<-B
        PROJ_STEP(kc + 1, arB, arA);              // LD(kc+3)->B, write(kc+2)<-A
    }
#undef PROJ_STEP

#pragma unroll
    for (int rg = 0; rg < 2; rg++) {
        const int rbase = m0 + 16 * rg + q4 * 4;  // C/D: row=(lane>>4)*4+r
#pragma unroll
        for (int nt = 0; nt < 2; nt++) {
            const int col = 32 * wn + 16 * nt + l16;  // C/D: col=lane&15
            float bvv = bias[col];
#pragma unroll
            for (int r = 0; r < 4; r++) {
                short h = f2bf(acc[rg][nt][r] + bvv);
                int grow = rbase + r;
                if (which == 0) {
                    qo[(size_t)grow * 128 + col] = h;
                } else if (which == 1) {
                    ko[(size_t)grow * 128 + col] = h;
                } else {
                    int bb = grow >> 11, s = grow & 2047;
                    vo[(size_t)bb * 262144 + (size_t)col * 2048 + s] = h;
                }
            }
        }
    }
}

// ---------------------------------------------------------------------------
// Kernel 2: flash attention, fixed-offset softmax (scores bounded; see r0).
// v8 = r7 structure (512 thr = 2 kv-pairs x 4 q-waves, dbuf, XCD swizzle,
// in-block merge) with REG-STAGED K/V (T14): global->VGPR (8 short8/thread)
// then ds_write_b128 with write-time XOR swizzle. LD(t+1) at iter start,
// compute(t), WR(t+1) at iter end (L2 latency ~300cy << compute lead), ONE
// barrier/iter. LDS 146KB, 1 block/CU.
// ---------------------------------------------------------------------------
__global__ __launch_bounds__(512) void flash_kernel(const short* __restrict__ qw,
                                                    const short* __restrict__ kw,
                                                    const short* __restrict__ vw,
                                                    float* __restrict__ out) {
    alignas(16) __shared__ short Kls[2][2][64 * 128];   // [buf][pair], slot=c^(r&15)
    alignas(16) __shared__ short Vls[2][2][128 * 64];   // [buf][pair], slot=c^(r&7)
    alignas(16) __shared__ short Pl[2][64][72];         // [pair][q][kv] (+8 pad)
    const int t = threadIdx.x;                       // 0..511
    const int wvi = t >> 6, L = t & 63;
    const int pr = wvi >> 2, wq = wvi & 3;           // pair, wave-in-pair
    const int pt = t & 255;                          // thread-in-pair
    const int q4 = L >> 4, l16 = L & 15;
    const int bid = blockIdx.x;
    const int b = bid & 7, bq = bid >> 3;            // batch->XCD affinity
    const short* qp = qw + (size_t)b * 262144 + (size_t)bq * 64 * 128;
    const short* kp = kw + (size_t)b * 262144;
    const short* vp = vw + (size_t)b * 262144;

    // Q-frags: wave-private, direct from global (row = 16*wq + l16)
    short8 qf[4];
#pragma unroll
    for (int ks = 0; ks < 4; ks++)
        qf[ks] = *(const short8*)(qp + (16 * wq + l16) * 128 + ks * 32 + q4 * 8);

    floatx4 oacc[8];
#pragma unroll
    for (int dt = 0; dt < 8; dt++) oacc[dt] = (floatx4)0.0f;
    float ps[4] = {0.f, 0.f, 0.f, 0.f};              // distributed row sums
    const float SL = (float)(0.08838834764831845 * 1.4426950408889634); // 1/sqrt(128)*log2(e)

    short8 kreg[4], vreg[4];                         // staging regs (L2-sourced)

    auto loadKV = [&](int kt) {
        const int kv0 = pr * 1024 + kt * 64;
#pragma unroll
        for (int j = 0; j < 4; j++) {                // K-tile [64r][16 slots]
            int s = j * 256 + pt, r = s >> 4, c = s & 15;
            kreg[j] = *(const short8*)(kp + (size_t)(kv0 + r) * 128 + c * 8);
        }
#pragma unroll
        for (int j = 0; j < 4; j++) {                // V-tile [128r][8 slots]
            int s = j * 256 + pt, r = s >> 3, c = s & 7;
            vreg[j] = *(const short8*)(vp + (size_t)r * 2048 + kv0 + c * 8);
        }
    };
    auto writeKV = [&](int buf) {
#pragma unroll
        for (int j = 0; j < 4; j++) {
            int s = j * 256 + pt, r = s >> 4, c = s & 15;
            *(short8*)&Kls[buf][pr][(r * 16 + (c ^ (r & 15))) * 8] = kreg[j];
        }
#pragma unroll
        for (int j = 0; j < 4; j++) {
            int s = j * 256 + pt, r = s >> 3, c = s & 7;
            *(short8*)&Vls[buf][pr][(r * 8 + (c ^ (r & 7))) * 8] = vreg[j];
        }
    };

    // prologue
    loadKV(0);
    writeKV(0);                                      // dataflow vmcnt waits
    asm volatile("s_waitcnt lgkmcnt(0)" ::: "memory");
    __builtin_amdgcn_sched_barrier(0);
    __builtin_amdgcn_s_barrier();

    for (int kt = 0; kt < 16; kt++) {
        const int cur = kt & 1;
        if (kt + 1 < 16) loadKV(kt + 1);             // regs in flight under compute
        __builtin_amdgcn_sched_barrier(0);

        // S = Q K^T  (16 q-rows x 64 kv per wave)
        floatx4 sa[4];
        __builtin_amdgcn_s_setprio(1);
#pragma unroll
        for (int nt = 0; nt < 4; nt++) {
            sa[nt] = (floatx4)0.0f;
#pragma unroll
            for (int ks = 0; ks < 4; ks++) {
                short8 bfr = *(short8*)&Kls[cur][pr][(16 * nt + l16) * 128 + ((4 * ks + q4) ^ l16) * 8];
                sa[nt] = MFMA16(qf[ks], bfr, sa[nt]);
            }
        }
        __builtin_amdgcn_s_setprio(0);

        // fixed-offset softmax: p = exp2(s*SL - 4); accumulate per-lane sums
#pragma unroll
        for (int nt = 0; nt < 4; nt++) {
#pragma unroll
            for (int r = 0; r < 4; r++) {
                float pv = __builtin_amdgcn_exp2f(sa[nt][r] * SL - 4.0f);
                ps[r] += pv;
                Pl[pr][16 * wq + q4 * 4 + r][16 * nt + l16] = f2bf(pv);
            }
        }

        // O += P V
        short8 pf0 = *(short8*)&Pl[pr][16 * wq + l16][q4 * 8];
        short8 pf1 = *(short8*)&Pl[pr][16 * wq + l16][32 + q4 * 8];
        __builtin_amdgcn_s_setprio(1);
#pragma unroll
        for (int dt = 0; dt < 8; dt++) {
            short8 v0 = *(short8*)&Vls[cur][pr][(16 * dt + l16) * 64 + (q4 ^ (l16 & 7)) * 8];
            short8 v1 = *(short8*)&Vls[cur][pr][(16 * dt + l16) * 64 + ((4 + q4) ^ (l16 & 7)) * 8];
            oacc[dt] = MFMA16(pf0, v0, oacc[dt]);
            oacc[dt] = MFMA16(pf1, v1, oacc[dt]);
        }
        __builtin_amdgcn_s_setprio(0);

        if (kt + 1 < 16) writeKV(cur ^ 1);           // into the released buffer
        asm volatile("s_waitcnt lgkmcnt(0)" ::: "memory");
        __builtin_amdgcn_sched_barrier(0);
        __builtin_amdgcn_s_barrier();
    }

    // one shuffle-reduce at the end: sum ps over the 16 col-lanes per row group
#pragma unroll
    for (int r = 0; r < 4; r++)
#pragma unroll
        for (int off = 1; off <= 8; off <<= 1)
            ps[r] += __shfl_xor(ps[r], off, 64);

    // ---- merge the two kv-halves (plain sums; no max needed) ----
    __syncthreads();
    float* Om = (float*)&Kls[0][0][0];  // 64x128 f32 = 32KB (= Kls buf0)
    float* Lm = (float*)&Vls[0][0][0];  // 64 floats
    if (pr == 1) {
#pragma unroll
        for (int dt = 0; dt < 8; dt++)
#pragma unroll
            for (int r = 0; r < 4; r++)
                Om[(16 * wq + q4 * 4 + r) * 128 + 16 * dt + l16] = oacc[dt][r];
        if (l16 == 0)
#pragma unroll
            for (int r = 0; r < 4; r++)
                Lm[16 * wq + q4 * 4 + r] = ps[r];
    }
    __syncthreads();
    if (pr == 0) {
        float inv[4];
#pragma unroll
        for (int r = 0; r < 4; r++)
            inv[r] = 1.0f / (ps[r] + Lm[16 * wq + q4 * 4 + r]);
#pragma unroll
        for (int dt = 0; dt < 8; dt++) {
#pragma unroll
            for (int r = 0; r < 4; r++) {
                int row = 16 * wq + q4 * 4 + r;
                int qrow = bq * 64 + row;
                out[((size_t)b * 2048 + qrow) * 128 + 16 * dt + l16] =
                    (oacc[dt][r] + Om[row * 128 + 16 * dt + l16]) * inv[r];
            }
        }
    }
}

extern "C" void kernel_launch(void* const* d_in, const int* in_sizes, int n_in,
                              void* d_out, int out_size, void* d_ws, size_t ws_size,
                              hipStream_t stream) {
    const float* query = (const float*)d_in[0];
    const float* key   = (const float*)d_in[1];
    const float* value = (const float*)d_in[2];
    const float* Wq    = (const float*)d_in[3];
    const float* bq    = (const float*)d_in[4];
    const float* Wk    = (const float*)d_in[5];
    const float* bk    = (const float*)d_in[6];
    const float* Wv    = (const float*)d_in[7];
    const float* bv    = (const float*)d_in[8];
    float* out = (float*)d_out;

    // ws layout (shorts): wtf[3][32][8][64][8] | q[16384][128] | k[16384][128] | vt[8][128][2048]
    short* wtf = (short*)d_ws;
    short* qws = wtf + 3 * 131072;
    short* kws = qws + 16384 * 128;
    short* vws = kws + 16384 * 128;

    wconv_kernel<<<1536, 256, 0, stream>>>(Wq, Wk, Wv, wtf);
    proj_kernel<<<dim3(512, 3), 256, 0, stream>>>(query, key, value, wtf,
                                                  bq, bk, bv, qws, kws, vws);
    flash_kernel<<<256, 512, 0, stream>>>(qws, kws, vws, out);
}

// Round 9
// 250.356 us; speedup vs baseline: 1.1606x; 1.1606x over previous
//
#include <hip/hip_runtime.h>

typedef __attribute__((ext_vector_type(8))) short short8;
typedef __attribute__((ext_vector_type(4))) float floatx4;

#define MFMA16(a, b, c) __builtin_amdgcn_mfma_f32_16x16x32_bf16(a, b, c, 0, 0, 0)

__device__ __forceinline__ short f2bf(float f) {
    unsigned int u = __float_as_uint(f);
    u = u + 0x7fffu + ((u >> 16) & 1u);
    return (short)(u >> 16);
}

// ---------------------------------------------------------------------------
// Kernel 0: convert Wq/Wk/Wv fp32 [1024][128] -> bf16 in MFMA FRAGMENT ORDER:
// wtf[which][ks(32)][nt(8)][lane(64)][e(8)], value = W[k][n] with
// n = 16*nt + (lane&15), k = 32*ks + 8*(lane>>4) + e.  A wave's B-fragment
// load is then ONE coalesced 1KB block (base + lane*16B): no gather, no LDS.
// ---------------------------------------------------------------------------
__global__ __launch_bounds__(256) void wconv_kernel(const float* __restrict__ Wq,
                                                    const float* __restrict__ Wk,
                                                    const float* __restrict__ Wv,
                                                    short* __restrict__ wtf) {
    int idx = blockIdx.x * 256 + threadIdx.x;   // < 3*131072
    int w = idx >> 17;
    int rem = idx & 131071;
    int ks = rem >> 12;
    int r2 = rem & 4095;
    int nt = r2 >> 9;
    int r3 = r2 & 511;
    int lane = r3 >> 3, e = r3 & 7;
    int q4 = lane >> 4, l16 = lane & 15;
    int n = 16 * nt + l16;
    int k = 32 * ks + 8 * q4 + e;
    const float* W = (w == 0) ? Wq : (w == 1) ? Wk : Wv;
    wtf[idx] = f2bf(W[k * 128 + n]);
}

// ---------------------------------------------------------------------------
// Kernel 1 (fused q/k/v): C = A[16384x1024](f32) * W (+bias) -> bf16.
// v9 = v8's structure (reg-path A staging: proven 2.9 TB/s in r8 even while
// spilling) with the SPILL FIXED: r8's WRITE_SIZE=201MB + VGPR=60 was the
// scratch signature of array-ref-lambda staging banks (rule #20). All
// staging state is now INDIVIDUALLY NAMED registers (a0..a3, b00..b31,
// acc00..acc11), straight-line loop body, no lambdas. Depth-1 prefetch:
// LOADA(t+1) at phase start, compute(t) covers HBM latency, LOADB(t+1)
// (younger than A(t+1)) + WRITEA at phase end (dataflow vmcnt wait), one
// barrier/phase. BM=32/BK=128, 32KB LDS, 4 blocks/CU, grid (512,3).
// ---------------------------------------------------------------------------
__global__ __launch_bounds__(256, 4) void proj_kernel(const float* __restrict__ Q,
                                                      const float* __restrict__ K,
                                                      const float* __restrict__ V,
                                                      const short* __restrict__ wtf,
                                                      const float* __restrict__ bq,
                                                      const float* __restrict__ bk,
                                                      const float* __restrict__ bv,
                                                      short* __restrict__ qo,
                                                      short* __restrict__ ko,
                                                      short* __restrict__ vo) {
    alignas(16) __shared__ float Asl[2][32 * 128];  // 16KB/buf: [row][32 slots], slot=c^(r&15)
    const int t = threadIdx.x;                    // 0..255
    const int wv = t >> 6, L = t & 63;
    const int wn = wv;                            // wave's col group (32 cols)
    const int q4 = L >> 4, l16 = L & 15;
    const int which = blockIdx.y;
    const float* A = (which == 0) ? Q : (which == 1) ? K : V;
    const short* Wf = wtf + which * 131072;
    const float* bias = (which == 0) ? bq : (which == 1) ? bk : bv;
    const int m0 = blockIdx.x * 32;

    // staging-load geometry: j-th load covers row j*8 + (t>>5), cols (t&31)*4
    const int tr = t >> 5, tc = (t & 31) << 2;
    const float* abase = A + (size_t)(m0 + tr) * 1024 + tc;
    // swizzled LDS slot for j-th write: (t&31) ^ ((j*8 + tr) & 15)
    const int sc0 = (t & 31) ^ (tr & 15);         // j=0,2 (j*8 ≡ 0 mod 16)
    const int sc1 = (t & 31) ^ ((8 + tr) & 15);   // j=1,3

    floatx4 acc00 = (floatx4)0.0f, acc01 = (floatx4)0.0f;
    floatx4 acc10 = (floatx4)0.0f, acc11 = (floatx4)0.0f;
    float4 a0, a1, a2, a3;                        // named staging bank
    short8 b00, b01, b10, b11, b20, b21, b30, b31;  // named B-frags

#define LOADA(K0)                                                           \
    {                                                                       \
        a0 = *(const float4*)(abase + (K0));                                \
        a1 = *(const float4*)(abase + 8192 + (K0));                         \
        a2 = *(const float4*)(abase + 16384 + (K0));                        \
        a3 = *(const float4*)(abase + 24576 + (K0));                        \
    }
#define WRITEA(BUF)                                                         \
    {                                                                       \
        *(float4*)&Asl[BUF][(tr * 32 + sc0) * 4] = a0;                      \
        *(float4*)&Asl[BUF][((8 + tr) * 32 + sc1) * 4] = a1;                \
        *(float4*)&Asl[BUF][((16 + tr) * 32 + sc0) * 4] = a2;               \
        *(float4*)&Asl[BUF][((24 + tr) * 32 + sc1) * 4] = a3;               \
    }
#define LOADB1(KC, KS, D0, D1)                                              \
    {                                                                       \
        const short* bp = Wf + (((size_t)(4 * (KC) + (KS)) * 8 + 2 * wn) * 64 + L) * 8; \
        D0 = *(const short8*)(bp);                                          \
        D1 = *(const short8*)(bp + 512);                                    \
    }
#define LOADB(KC)                                                           \
    {                                                                       \
        LOADB1(KC, 0, b00, b01); LOADB1(KC, 1, b10, b11);                   \
        LOADB1(KC, 2, b20, b21); LOADB1(KC, 3, b30, b31);                   \
    }
#define CSTEP(CUR, KS, B0, B1)                                              \
    {                                                                       \
        int c0 = 8 * (KS) + 2 * q4;                                         \
        float4 f0 = *(float4*)&Asl[CUR][(l16 * 32 + (c0 ^ l16)) * 4];       \
        float4 f1 = *(float4*)&Asl[CUR][(l16 * 32 + ((c0 + 1) ^ l16)) * 4]; \
        float4 g0 = *(float4*)&Asl[CUR][((16 + l16) * 32 + (c0 ^ l16)) * 4]; \
        float4 g1 = *(float4*)&Asl[CUR][((16 + l16) * 32 + ((c0 + 1) ^ l16)) * 4]; \
        short8 af0, af1;                                                    \
        af0[0] = f2bf(f0.x); af0[1] = f2bf(f0.y); af0[2] = f2bf(f0.z); af0[3] = f2bf(f0.w); \
        af0[4] = f2bf(f1.x); af0[5] = f2bf(f1.y); af0[6] = f2bf(f1.z); af0[7] = f2bf(f1.w); \
        af1[0] = f2bf(g0.x); af1[1] = f2bf(g0.y); af1[2] = f2bf(g0.z); af1[3] = f2bf(g0.w); \
        af1[4] = f2bf(g1.x); af1[5] = f2bf(g1.y); af1[6] = f2bf(g1.z); af1[7] = f2bf(g1.w); \
        __builtin_amdgcn_s_setprio(1);                                      \
        acc00 = MFMA16(af0, B0, acc00);                                     \
        acc01 = MFMA16(af0, B1, acc01);                                     \
        acc10 = MFMA16(af1, B0, acc10);                                     \
        acc11 = MFMA16(af1, B1, acc11);                                     \
        __builtin_amdgcn_s_setprio(0);                                      \
    }

    // prologue: A(0) -> regs -> LDS buf0; B(0) -> regs; barrier
    LOADA(0);
    LOADB(0);
    WRITEA(0);                                    // dataflow vmcnt wait on a0..a3
    asm volatile("s_waitcnt lgkmcnt(0)" ::: "memory");
    __builtin_amdgcn_sched_barrier(0);
    __builtin_amdgcn_s_barrier();

    for (int kc = 0; kc < 8; kc++) {
        const int cur = kc & 1;
        if (kc + 1 < 8) LOADA((kc + 1) * 128);    // HBM loads, land during compute
        __builtin_amdgcn_sched_barrier(0);
        CSTEP(cur, 0, b00, b01);
        CSTEP(cur, 1, b10, b11);
        CSTEP(cur, 2, b20, b21);
        CSTEP(cur, 3, b30, b31);
        if (kc + 1 < 8) {
            LOADB(kc + 1);                        // L2, younger than A(kc+1)
            WRITEA(cur ^ 1);                      // waits A(kc+1) only (older)
        }
        asm volatile("s_waitcnt lgkmcnt(0)" ::: "memory");
        __builtin_amdgcn_sched_barrier(0);
        __builtin_amdgcn_s_barrier();
    }
#undef LOADA
#undef WRITEA
#undef LOADB1
#undef LOADB
#undef CSTEP

    // epilogue: C/D row=(lane>>4)*4+r, col=lane&15
    {
        const int col0 = 32 * wn + l16, col1 = 32 * wn + 16 + l16;
        const float bv0 = bias[col0], bv1 = bias[col1];
#pragma unroll
        for (int r = 0; r < 4; r++) {
            int grow0 = m0 + q4 * 4 + r;
            int grow1 = m0 + 16 + q4 * 4 + r;
            short h00 = f2bf(acc00[r] + bv0), h01 = f2bf(acc01[r] + bv1);
            short h10 = f2bf(acc10[r] + bv0), h11 = f2bf(acc11[r] + bv1);
            if (which == 0) {
                qo[(size_t)grow0 * 128 + col0] = h00;
                qo[(size_t)grow0 * 128 + col1] = h01;
                qo[(size_t)grow1 * 128 + col0] = h10;
                qo[(size_t)grow1 * 128 + col1] = h11;
            } else if (which == 1) {
                ko[(size_t)grow0 * 128 + col0] = h00;
                ko[(size_t)grow0 * 128 + col1] = h01;
                ko[(size_t)grow1 * 128 + col0] = h10;
                ko[(size_t)grow1 * 128 + col1] = h11;
            } else {
                int bb0 = grow0 >> 11, s0 = grow0 & 2047;
                int bb1 = grow1 >> 11, s1 = grow1 & 2047;
                vo[(size_t)bb0 * 262144 + (size_t)col0 * 2048 + s0] = h00;
                vo[(size_t)bb0 * 262144 + (size_t)col1 * 2048 + s0] = h01;
                vo[(size_t)bb1 * 262144 + (size_t)col0 * 2048 + s1] = h10;
                vo[(size_t)bb1 * 262144 + (size_t)col1 * 2048 + s1] = h11;
            }
        }
    }
}

// ---------------------------------------------------------------------------
// Kernel 2: flash attention, fixed-offset softmax (scores bounded; see r0).
// UNCHANGED from r8 (single-variable round: only proj's spill is fixed).
// ---------------------------------------------------------------------------
__global__ __launch_bounds__(512) void flash_kernel(const short* __restrict__ qw,
                                                    const short* __restrict__ kw,
                                                    const short* __restrict__ vw,
                                                    float* __restrict__ out) {
    alignas(16) __shared__ short Kls[2][2][64 * 128];   // [buf][pair], slot=c^(r&15)
    alignas(16) __shared__ short Vls[2][2][128 * 64];   // [buf][pair], slot=c^(r&7)
    alignas(16) __shared__ short Pl[2][64][72];         // [pair][q][kv] (+8 pad)
    const int t = threadIdx.x;                       // 0..511
    const int wvi = t >> 6, L = t & 63;
    const int pr = wvi >> 2, wq = wvi & 3;           // pair, wave-in-pair
    const int pt = t & 255;                          // thread-in-pair
    const int q4 = L >> 4, l16 = L & 15;
    const int bid = blockIdx.x;
    const int b = bid & 7, bq = bid >> 3;            // batch->XCD affinity
    const short* qp = qw + (size_t)b * 262144 + (size_t)bq * 64 * 128;
    const short* kp = kw + (size_t)b * 262144;
    const short* vp = vw + (size_t)b * 262144;

    // Q-frags: wave-private, direct from global (row = 16*wq + l16)
    short8 qf[4];
#pragma unroll
    for (int ks = 0; ks < 4; ks++)
        qf[ks] = *(const short8*)(qp + (16 * wq + l16) * 128 + ks * 32 + q4 * 8);

    floatx4 oacc[8];
#pragma unroll
    for (int dt = 0; dt < 8; dt++) oacc[dt] = (floatx4)0.0f;
    float ps[4] = {0.f, 0.f, 0.f, 0.f};              // distributed row sums
    const float SL = (float)(0.08838834764831845 * 1.4426950408889634); // 1/sqrt(128)*log2(e)

    short8 kreg[4], vreg[4];                         // staging regs (L2-sourced)

    auto loadKV = [&](int kt) {
        const int kv0 = pr * 1024 + kt * 64;
#pragma unroll
        for (int j = 0; j < 4; j++) {                // K-tile [64r][16 slots]
            int s = j * 256 + pt, r = s >> 4, c = s & 15;
            kreg[j] = *(const short8*)(kp + (size_t)(kv0 + r) * 128 + c * 8);
        }
#pragma unroll
        for (int j = 0; j < 4; j++) {                // V-tile [128r][8 slots]
            int s = j * 256 + pt, r = s >> 3, c = s & 7;
            vreg[j] = *(const short8*)(vp + (size_t)r * 2048 + kv0 + c * 8);
        }
    };
    auto writeKV = [&](int buf) {
#pragma unroll
        for (int j = 0; j < 4; j++) {
            int s = j * 256 + pt, r = s >> 4, c = s & 15;
            *(short8*)&Kls[buf][pr][(r * 16 + (c ^ (r & 15))) * 8] = kreg[j];
        }
#pragma unroll
        for (int j = 0; j < 4; j++) {
            int s = j * 256 + pt, r = s >> 3, c = s & 7;
            *(short8*)&Vls[buf][pr][(r * 8 + (c ^ (r & 7))) * 8] = vreg[j];
        }
    };

    // prologue
    loadKV(0);
    writeKV(0);                                      // dataflow vmcnt waits
    asm volatile("s_waitcnt lgkmcnt(0)" ::: "memory");
    __builtin_amdgcn_sched_barrier(0);
    __builtin_amdgcn_s_barrier();

    for (int kt = 0; kt < 16; kt++) {
        const int cur = kt & 1;
        if (kt + 1 < 16) loadKV(kt + 1);             // regs in flight under compute
        __builtin_amdgcn_sched_barrier(0);

        // S = Q K^T  (16 q-rows x 64 kv per wave)
        floatx4 sa[4];
        __builtin_amdgcn_s_setprio(1);
#pragma unroll
        for (int nt = 0; nt < 4; nt++) {
            sa[nt] = (floatx4)0.0f;
#pragma unroll
            for (int ks = 0; ks < 4; ks++) {
                short8 bfr = *(short8*)&Kls[cur][pr][(16 * nt + l16) * 128 + ((4 * ks + q4) ^ l16) * 8];
                sa[nt] = MFMA16(qf[ks], bfr, sa[nt]);
            }
        }
        __builtin_amdgcn_s_setprio(0);

        // fixed-offset softmax: p = exp2(s*SL - 4); accumulate per-lane sums
#pragma unroll
        for (int nt = 0; nt < 4; nt++) {
#pragma unroll
            for (int r = 0; r < 4; r++) {
                float pv = __builtin_amdgcn_exp2f(sa[nt][r] * SL - 4.0f);
                ps[r] += pv;
                Pl[pr][16 * wq + q4 * 4 + r][16 * nt + l16] = f2bf(pv);
            }
        }

        // O += P V
        short8 pf0 = *(short8*)&Pl[pr][16 * wq + l16][q4 * 8];
        short8 pf1 = *(short8*)&Pl[pr][16 * wq + l16][32 + q4 * 8];
        __builtin_amdgcn_s_setprio(1);
#pragma unroll
        for (int dt = 0; dt < 8; dt++) {
            short8 v0 = *(short8*)&Vls[cur][pr][(16 * dt + l16) * 64 + (q4 ^ (l16 & 7)) * 8];
            short8 v1 = *(short8*)&Vls[cur][pr][(16 * dt + l16) * 64 + ((4 + q4) ^ (l16 & 7)) * 8];
            oacc[dt] = MFMA16(pf0, v0, oacc[dt]);
            oacc[dt] = MFMA16(pf1, v1, oacc[dt]);
        }
        __builtin_amdgcn_s_setprio(0);

        if (kt + 1 < 16) writeKV(cur ^ 1);           // into the released buffer
        asm volatile("s_waitcnt lgkmcnt(0)" ::: "memory");
        __builtin_amdgcn_sched_barrier(0);
        __builtin_amdgcn_s_barrier();
    }

    // one shuffle-reduce at the end: sum ps over the 16 col-lanes per row group
#pragma unroll
    for (int r = 0; r < 4; r++)
#pragma unroll
        for (int off = 1; off <= 8; off <<= 1)
            ps[r] += __shfl_xor(ps[r], off, 64);

    // ---- merge the two kv-halves (plain sums; no max needed) ----
    __syncthreads();
    float* Om = (float*)&Kls[0][0][0];  // 64x128 f32 = 32KB (= Kls buf0)
    float* Lm = (float*)&Vls[0][0][0];  // 64 floats
    if (pr == 1) {
#pragma unroll
        for (int dt = 0; dt < 8; dt++)
#pragma unroll
            for (int r = 0; r < 4; r++)
                Om[(16 * wq + q4 * 4 + r) * 128 + 16 * dt + l16] = oacc[dt][r];
        if (l16 == 0)
#pragma unroll
            for (int r = 0; r < 4; r++)
                Lm[16 * wq + q4 * 4 + r] = ps[r];
    }
    __syncthreads();
    if (pr == 0) {
        float inv[4];
#pragma unroll
        for (int r = 0; r < 4; r++)
            inv[r] = 1.0f / (ps[r] + Lm[16 * wq + q4 * 4 + r]);
#pragma unroll
        for (int dt = 0; dt < 8; dt++) {
#pragma unroll
            for (int r = 0; r < 4; r++) {
                int row = 16 * wq + q4 * 4 + r;
                int qrow = bq * 64 + row;
                out[((size_t)b * 2048 + qrow) * 128 + 16 * dt + l16] =
                    (oacc[dt][r] + Om[row * 128 + 16 * dt + l16]) * inv[r];
            }
        }
    }
}

extern "C" void kernel_launch(void* const* d_in, const int* in_sizes, int n_in,
                              void* d_out, int out_size, void* d_ws, size_t ws_size,
                              hipStream_t stream) {
    const float* query = (const float*)d_in[0];
    const float* key   = (const float*)d_in[1];
    const float* value = (const float*)d_in[2];
    const float* Wq    = (const float*)d_in[3];
    const float* bq    = (const float*)d_in[4];
    const float* Wk    = (const float*)d_in[5];
    const float* bk    = (const float*)d_in[6];
    const float* Wv    = (const float*)d_in[7];
    const float* bv    = (const float*)d_in[8];
    float* out = (float*)d_out;

    // ws layout (shorts): wtf[3][32][8][64][8] | q[16384][128] | k[16384][128] | vt[8][128][2048]
    short* wtf = (short*)d_ws;
    short* qws = wtf + 3 * 131072;
    short* kws = qws + 16384 * 128;
    short* vws = kws + 16384 * 128;

    wconv_kernel<<<1536, 256, 0, stream>>>(Wq, Wk, Wv, wtf);
    proj_kernel<<<dim3(512, 3), 256, 0, stream>>>(query, key, value, wtf,
                                                  bq, bk, bv, qws, kws, vws);
    flash_kernel<<<256, 512, 0, stream>>>(qws, kws, vws, out);
}